// Round 1
// baseline (74.168 us; speedup 1.0000x reference)
//
#include <hip/hip_runtime.h>

#define NL 50
#define V_DIM 4096

__global__ __launch_bounds__(256) void ZWeightedSum_kernel(
    const float* __restrict__ x,      // (B, V, 2)
    const float* __restrict__ weight, // (NL, 1)
    const float* __restrict__ bias,   // (NL,)
    float* __restrict__ out)          // (B,)
{
    __shared__ float s_low[NL];
    __shared__ float s_high[NL];
    __shared__ float s_w[NL];
    __shared__ float s_bw;
    __shared__ float s_part[4];

    const int t = threadIdx.x;

    // Build edges exactly as numpy does: float64 arange, /200.0, *(120.0/200.0), cast f32.
    if (t < NL) {
        double l = (double)t;
        double lowd, highd;
        if (t < 25) {
            lowd  = l;
            highd = l + 1.0;
        } else {
            lowd  = 25.0 + 7.0 * (l - 25.0);
            highd = 32.0 + 7.0 * (l - 25.0);
        }
        const double f = 120.0 / 200.0;
        s_low[t]  = (float)((lowd  / 200.0) * f);
        s_high[t] = (float)((highd / 200.0) * f);
        s_w[t]    = weight[t];
    }
    __syncthreads();

    if (t == 0) {
        float bw = 0.0f;
        #pragma unroll
        for (int l = 0; l < NL; ++l) bw += bias[l] * s_w[l];
        s_bw = bw;
    }

    // One block per batch row. 4096 (z,val) pairs = 2048 float4s.
    const int b = blockIdx.x;
    const float4* xb = (const float4*)(x + (size_t)b * (size_t)(V_DIM * 2));

    float acc = 0.0f;
    #pragma unroll
    for (int it = 0; it < (V_DIM * 2 / 4) / 256; ++it) {
        const int i = t + it * 256;
        float4 p = xb[i];   // (z0, v0, z1, v1)
        float w0 = 0.0f, w1 = 0.0f;
        #pragma unroll
        for (int l = 0; l < NL; ++l) {
            const float lo = s_low[l];
            const float hi = s_high[l];
            if (p.x > lo && p.x < hi) w0 = s_w[l];
            if (p.z > lo && p.z < hi) w1 = s_w[l];
        }
        acc += p.y * w0 + p.w * w1;
    }

    // wave-64 butterfly reduce
    #pragma unroll
    for (int off = 32; off > 0; off >>= 1)
        acc += __shfl_down(acc, off, 64);

    const int wave = t >> 6;
    if ((t & 63) == 0) s_part[wave] = acc;
    __syncthreads();

    if (t == 0) {
        out[b] = s_part[0] + s_part[1] + s_part[2] + s_part[3] + s_bw;
    }
}

extern "C" void kernel_launch(void* const* d_in, const int* in_sizes, int n_in,
                              void* d_out, int out_size, void* d_ws, size_t ws_size,
                              hipStream_t stream) {
    const float* x      = (const float*)d_in[0];
    const float* weight = (const float*)d_in[1];
    const float* bias   = (const float*)d_in[2];
    float* out          = (float*)d_out;

    const int B = in_sizes[0] / (V_DIM * 2);  // 256
    ZWeightedSum_kernel<<<B, 256, 0, stream>>>(x, weight, bias, out);
}

// Round 2
// 62.664 us; speedup vs baseline: 1.1836x; 1.1836x over previous
//
#include <hip/hip_runtime.h>

#define NL 50
#define V_DIM 4096
#define THREADS 1024

__global__ __launch_bounds__(1024) void ZWeightedSum_kernel(
    const float* __restrict__ x,      // (B, V, 2)
    const float* __restrict__ weight, // (NL, 1)
    const float* __restrict__ bias,   // (NL,)
    float* __restrict__ out)          // (B,)
{
    // 64-entry tables (50 real + sentinels) for scattered LDS lookup
    __shared__ float s_lo[64];
    __shared__ float s_hi[64];
    __shared__ float s_w[64];
    __shared__ float s_part[16];

    const int t = threadIdx.x;

    if (t < 64) {
        float lo, hi, w;
        if (t < NL) {
            // exact numpy edge construction: double arange, /200.0, *(120/200), cast f32
            double l = (double)t;
            double lowd, highd;
            if (t < 25) { lowd = l;                    highd = l + 1.0; }
            else        { lowd = 25.0 + 7.0*(l-25.0);  highd = 32.0 + 7.0*(l-25.0); }
            const double f = 120.0 / 200.0;
            lo = (float)((lowd  / 200.0) * f);
            hi = (float)((highd / 200.0) * f);
            w  = weight[t];
        } else {
            lo = 1e30f; hi = -1e30f; w = 0.0f;  // sentinel: never matches
        }
        s_lo[t] = lo; s_hi[t] = hi; s_w[t] = w;
    }
    __syncthreads();

    // bias·weight term, thread 0 only (uses local register, read back at epilogue)
    float bw = 0.0f;
    if (t == 0) {
        #pragma unroll
        for (int l = 0; l < NL; ++l) bw += bias[l] * s_w[l];
    }

    const int b = blockIdx.x;
    const float4* xb = (const float4*)(x + (size_t)b * (size_t)(V_DIM * 2));
    const float C1 = 1000.0f / 3.0f;   // 1 / bin_width for the unit-stride region

    float acc = 0.0f;
    #pragma unroll
    for (int it = 0; it < (V_DIM / 2) / THREADS; ++it) {   // 2 iterations
        float4 p = xb[t + it * THREADS];   // (z0, v0, z1, v1)
        float zz[2] = { p.x, p.z };
        float vv[2] = { p.y, p.w };
        #pragma unroll
        for (int e = 0; e < 2; ++e) {
            const float z = zz[e];
            const float u = z * C1;
            // candidate bin (truncation == floor since u >= 0)
            int ca = (int)u;
            int cb = 25 + (int)((u - 25.0f) * (1.0f / 7.0f));
            int c  = (u < 25.5f) ? ca : cb;
            c = min(c, 49);
            // verify c-1, c, c+1 against exact f32 edges (absorbs fp rounding)
            float weff = 0.0f;
            #pragma unroll
            for (int j = 0; j <= 2; ++j) {
                int l = c - 1 + j;
                l = max(0, min(l, 63));
                if (z > s_lo[l] && z < s_hi[l]) weff = s_w[l];
            }
            acc += vv[e] * weff;
        }
    }

    // wave-64 butterfly reduce
    #pragma unroll
    for (int off = 32; off > 0; off >>= 1)
        acc += __shfl_down(acc, off, 64);

    if ((t & 63) == 0) s_part[t >> 6] = acc;
    __syncthreads();

    if (t == 0) {
        float s = bw;
        #pragma unroll
        for (int i = 0; i < 16; ++i) s += s_part[i];
        out[b] = s;
    }
}

extern "C" void kernel_launch(void* const* d_in, const int* in_sizes, int n_in,
                              void* d_out, int out_size, void* d_ws, size_t ws_size,
                              hipStream_t stream) {
    const float* x      = (const float*)d_in[0];
    const float* weight = (const float*)d_in[1];
    const float* bias   = (const float*)d_in[2];
    float* out          = (float*)d_out;

    const int B = in_sizes[0] / (V_DIM * 2);  // 256
    ZWeightedSum_kernel<<<B, THREADS, 0, stream>>>(x, weight, bias, out);
}

// Round 3
// 62.635 us; speedup vs baseline: 1.1841x; 1.0005x over previous
//
#include <hip/hip_runtime.h>

#define NL 50
#define V_DIM 4096
#define THREADS 1024

__global__ __launch_bounds__(1024) void ZWeightedSum_kernel(
    const float* __restrict__ x,      // (B, V, 2)
    const float* __restrict__ weight, // (NL, 1)
    const float* __restrict__ bias,   // (NL,)
    float* __restrict__ out)          // (B,)
{
    // packed (lo, hi, w, 0) table; 50 real entries + sentinels, one ds_read_b128 per probe
    __shared__ float4 s_tab[64];
    __shared__ float  s_part[16];

    const int t = threadIdx.x;

    if (t < 64) {
        float lo, hi, w;
        if (t < NL) {
            // exact numpy edge construction: double arange, /200.0, *(120/200), cast f32
            double l = (double)t;
            double lowd, highd;
            if (t < 25) { lowd = l;                    highd = l + 1.0; }
            else        { lowd = 25.0 + 7.0*(l-25.0);  highd = 32.0 + 7.0*(l-25.0); }
            const double f = 120.0 / 200.0;
            lo = (float)((lowd  / 200.0) * f);
            hi = (float)((highd / 200.0) * f);
            w  = weight[t];
        } else {
            lo = 1e30f; hi = -1e30f; w = 0.0f;  // sentinel: never matches
        }
        s_tab[t] = make_float4(lo, hi, w, 0.0f);
    }
    __syncthreads();

    // bias·weight term (thread 0 only; bins' weights read from LDS table)
    float bw = 0.0f;
    if (t == 0) {
        #pragma unroll
        for (int l = 0; l < NL; ++l) bw += bias[l] * s_tab[l].z;
    }

    const int b = blockIdx.x;
    const float4* xb = (const float4*)(x + (size_t)b * (size_t)(V_DIM * 2));
    const float C1 = 1000.0f / 3.0f;   // 1 / bin_width for the unit-stride region

    float acc = 0.0f;
    #pragma unroll
    for (int it = 0; it < (V_DIM / 2) / THREADS; ++it) {   // 2 iterations
        float4 p = xb[t + it * THREADS];   // (z0, v0, z1, v1)
        float zz[2] = { p.x, p.z };
        float vv[2] = { p.y, p.w };
        #pragma unroll
        for (int e = 0; e < 2; ++e) {
            const float z = zz[e];
            const float u = z * C1;
            // candidate bin (truncation == floor since u >= 0)
            int ca = (int)u;
            int cb = 25 + (int)((u - 25.0f) * (1.0f / 7.0f));
            int c  = (u < 25.5f) ? ca : cb;
            c = min(c, 49);
            // verify c-1, c, c+1 against exact f32 edges (absorbs fp rounding)
            float weff = 0.0f;
            #pragma unroll
            for (int j = 0; j <= 2; ++j) {
                int l = max(0, min(c - 1 + j, 63));
                float4 e4 = s_tab[l];        // one ds_read_b128
                if (z > e4.x && z < e4.y) weff = e4.z;
            }
            acc += vv[e] * weff;
        }
    }

    // wave-64 butterfly reduce
    #pragma unroll
    for (int off = 32; off > 0; off >>= 1)
        acc += __shfl_down(acc, off, 64);

    if ((t & 63) == 0) s_part[t >> 6] = acc;
    __syncthreads();

    if (t == 0) {
        float s = bw;
        #pragma unroll
        for (int i = 0; i < 16; ++i) s += s_part[i];
        out[b] = s;
    }
}

extern "C" void kernel_launch(void* const* d_in, const int* in_sizes, int n_in,
                              void* d_out, int out_size, void* d_ws, size_t ws_size,
                              hipStream_t stream) {
    const float* x      = (const float*)d_in[0];
    const float* weight = (const float*)d_in[1];
    const float* bias   = (const float*)d_in[2];
    float* out          = (float*)d_out;

    const int B = in_sizes[0] / (V_DIM * 2);  // 256
    ZWeightedSum_kernel<<<B, THREADS, 0, stream>>>(x, weight, bias, out);
}